// Round 4
// baseline (3218.487 us; speedup 1.0000x reference)
//
#include <hip/hip_runtime.h>
#include <hip/hip_bf16.h>

#define H 256
#define TYPE_DIM 64
#define EIN (2*H + TYPE_DIM)   // 576
#define N_ENTS 100000
#define N_EDGES 200000
#define EPB 16                  // edges per block
#define NPB 8                   // nodes per block

typedef __hip_bfloat16 bf16;

__device__ __forceinline__ float b2f(bf16 x) { return __bfloat162float(x); }

// ---------------- transpose W_ih/W_hh (768x256 f32 -> 256x768 bf16) --------
__global__ void transpose_kernel(const float* __restrict__ Wih,
                                 const float* __restrict__ Whh,
                                 bf16* __restrict__ WTih,
                                 bf16* __restrict__ WThh) {
    int j = blockIdx.x;      // 0..767 (row of W)
    int k = threadIdx.x;     // 0..255 (col of W)
    float a = Wih[j * H + k];
    float b = Whh[j * H + k];
    WTih[k * 768 + j] = __float2bfloat16(a);
    WThh[k * 768 + j] = __float2bfloat16(b);
}

// ---------------- edge MLP + scatter-add (f32 agg in d_out) ----------------
__global__ __launch_bounds__(256) void edge_kernel(
    const float* __restrict__ node_emb, const float* __restrict__ type_emb,
    const float* __restrict__ W_edge, const float* __restrict__ b_edge,
    const float* __restrict__ ln_g, const float* __restrict__ ln_b,
    const int* __restrict__ src, const int* __restrict__ dst,
    const int* __restrict__ et,
    float* __restrict__ agg,           // = d_out, f32 accumulator
    unsigned int* __restrict__ cntw) { // packed u16 counts, 2 per word
    __shared__ float ein[EPB][EIN];
    __shared__ int sidx[EPB], didx[EPB], tidx[EPB];
    __shared__ float wred[8];
    __shared__ float stats[2];

    const int tid = threadIdx.x;
    const int e0 = blockIdx.x * EPB;

    if (tid < EPB) {
        sidx[tid] = src[e0 + tid];
        didx[tid] = dst[e0 + tid];
        tidx[tid] = et[e0 + tid];
    }
    __syncthreads();

    for (int e = 0; e < EPB; e++) {
        ein[e][tid]     = node_emb[(size_t)sidx[e] * H + tid];
        ein[e][H + tid] = node_emb[(size_t)didx[e] * H + tid];
        if (tid < TYPE_DIM)
            ein[e][2 * H + tid] = type_emb[(size_t)tidx[e] * TYPE_DIM + tid];
    }
    __syncthreads();

    float acc[EPB];
    const float bias = b_edge[tid];
    #pragma unroll
    for (int e = 0; e < EPB; e++) acc[e] = bias;

    #pragma unroll 4
    for (int k = 0; k < EIN; k++) {
        float w = W_edge[k * H + tid];        // coalesced column read
        #pragma unroll
        for (int e = 0; e < EPB; e++) acc[e] += ein[e][k] * w;  // LDS broadcast
    }

    const float g = ln_g[tid], bb = ln_b[tid];
    const int lane = tid & 63, wid = tid >> 6;

    for (int e = 0; e < EPB; e++) {
        float v = acc[e];
        float s1 = v, s2 = v * v;
        for (int o = 32; o > 0; o >>= 1) {
            s1 += __shfl_down(s1, o, 64);
            s2 += __shfl_down(s2, o, 64);
        }
        if (lane == 0) { wred[wid] = s1; wred[4 + wid] = s2; }
        __syncthreads();
        if (tid == 0) {
            float t1 = wred[0] + wred[1] + wred[2] + wred[3];
            float t2 = wred[4] + wred[5] + wred[6] + wred[7];
            float m = t1 / (float)H;
            float var = fmaxf(t2 / (float)H - m * m, 0.0f);
            stats[0] = m; stats[1] = rsqrtf(var + 1e-5f);
        }
        __syncthreads();
        float m = stats[0], is = stats[1];
        float y = (v - m) * is * g + bb;
        acc[e] = fmaxf(y, 0.0f);   // relu'd edge_feat element `tid`
    }

    #pragma unroll
    for (int e = 0; e < EPB; e++)
        atomicAdd(&agg[(size_t)didx[e] * H + tid], acc[e]);
    if (tid < EPB) {
        int d = didx[tid];
        atomicAdd(&cntw[d >> 1], (d & 1) ? 65536u : 1u);  // u16-packed count
    }
}

// ---------------- gate fusion + GRU + LN ----------------
__global__ __launch_bounds__(256) void node_kernel(
    const float* __restrict__ node_emb, const float* __restrict__ h_prev,
    const float* __restrict__ W_gate, const float* __restrict__ b_gate,
    const float* __restrict__ lng_g, const float* __restrict__ lng_b,
    const bf16* __restrict__ WT_ih, const bf16* __restrict__ WT_hh,
    const float* __restrict__ b_ih, const float* __restrict__ b_hh,
    const float* __restrict__ lnr_g, const float* __restrict__ lnr_b,
    const unsigned int* __restrict__ cntw,
    float* __restrict__ out) {   // out doubles as agg (f32) on input
    __shared__ float xn[NPB][H];   // node_emb, later overwritten with x
    __shared__ float en[NPB][H];   // edge_enh
    __shared__ float hp[NPB][H];   // h_prev
    __shared__ float wred[8];
    __shared__ float stats[2];

    const int tid = threadIdx.x;
    const int n0 = blockIdx.x * NPB;
    const int lane = tid & 63, wid = tid >> 6;

    for (int e = 0; e < NPB; e++) {
        size_t n = (size_t)(n0 + e);
        unsigned int cw = cntw[n >> 1];
        float c = (float)((cw >> ((n & 1) * 16)) & 0xFFFFu);
        float rc = 1.0f / fmaxf(c, 1.0f);
        xn[e][tid] = node_emb[n * H + tid];
        hp[e][tid] = h_prev[n * H + tid];
        en[e][tid] = out[n * H + tid] * rc;   // agg (f32) lives in out
    }
    __syncthreads();

    // ---- gate GEMV batch: u = concat(node, enh) @ W_gate + b_gate ----
    float accg[NPB];
    const float bg = b_gate[tid];
    #pragma unroll
    for (int e = 0; e < NPB; e++) accg[e] = bg;

    #pragma unroll 4
    for (int k = 0; k < H; k++) {
        float w1 = W_gate[k * H + tid];
        float w2 = W_gate[(k + H) * H + tid];
        #pragma unroll
        for (int e = 0; e < NPB; e++)
            accg[e] += xn[e][k] * w1 + en[e][k] * w2;
    }

    const float gg = lng_g[tid], gb = lng_b[tid];
    for (int e = 0; e < NPB; e++) {
        float v = accg[e];
        float s1 = v, s2 = v * v;
        for (int o = 32; o > 0; o >>= 1) {
            s1 += __shfl_down(s1, o, 64);
            s2 += __shfl_down(s2, o, 64);
        }
        if (lane == 0) { wred[wid] = s1; wred[4 + wid] = s2; }
        __syncthreads();
        if (tid == 0) {
            float t1 = wred[0] + wred[1] + wred[2] + wred[3];
            float t2 = wred[4] + wred[5] + wred[6] + wred[7];
            float m = t1 / (float)H;
            float var = fmaxf(t2 / (float)H - m * m, 0.0f);
            stats[0] = m; stats[1] = rsqrtf(var + 1e-5f);
        }
        __syncthreads();
        float m = stats[0], is = stats[1];
        float u = (v - m) * is * gg + gb;
        float gate = 1.0f / (1.0f + __expf(-u));
        float xnv = xn[e][tid];
        float env = en[e][tid];
        float fused = gate * xnv + (1.0f - gate) * env;
        xn[e][tid] = 0.2f * xnv + 0.8f * fused;   // x
    }
    __syncthreads();

    // ---- GRU GEMV batch: gi = x @ W_ih^T, gh = h_prev @ W_hh^T ----
    float gi0[NPB], gi1[NPB], gi2[NPB], gh0[NPB], gh1[NPB], gh2[NPB];
    const float bi0 = b_ih[tid], bi1 = b_ih[H + tid], bi2 = b_ih[2 * H + tid];
    const float bh0 = b_hh[tid], bh1 = b_hh[H + tid], bh2 = b_hh[2 * H + tid];
    #pragma unroll
    for (int e = 0; e < NPB; e++) {
        gi0[e] = bi0; gi1[e] = bi1; gi2[e] = bi2;
        gh0[e] = bh0; gh1[e] = bh1; gh2[e] = bh2;
    }

    #pragma unroll 2
    for (int k = 0; k < H; k++) {
        float wi0 = b2f(WT_ih[k * 768 + tid]);
        float wi1 = b2f(WT_ih[k * 768 + H + tid]);
        float wi2 = b2f(WT_ih[k * 768 + 2 * H + tid]);
        float wh0 = b2f(WT_hh[k * 768 + tid]);
        float wh1 = b2f(WT_hh[k * 768 + H + tid]);
        float wh2 = b2f(WT_hh[k * 768 + 2 * H + tid]);
        #pragma unroll
        for (int e = 0; e < NPB; e++) {
            float xk = xn[e][k], hk = hp[e][k];
            gi0[e] += xk * wi0; gi1[e] += xk * wi1; gi2[e] += xk * wi2;
            gh0[e] += hk * wh0; gh1[e] += hk * wh1; gh2[e] += hk * wh2;
        }
    }

    const float rg = lnr_g[tid], rb = lnr_b[tid];
    for (int e = 0; e < NPB; e++) {
        float r = 1.0f / (1.0f + __expf(-(gi0[e] + gh0[e])));
        float z = 1.0f / (1.0f + __expf(-(gi1[e] + gh1[e])));
        float nn = tanhf(gi2[e] + r * gh2[e]);
        float hpv = hp[e][tid];
        float h = (1.0f - z) * nn + z * hpv;
        float s1 = h, s2 = h * h;
        for (int o = 32; o > 0; o >>= 1) {
            s1 += __shfl_down(s1, o, 64);
            s2 += __shfl_down(s2, o, 64);
        }
        if (lane == 0) { wred[wid] = s1; wred[4 + wid] = s2; }
        __syncthreads();
        if (tid == 0) {
            float t1 = wred[0] + wred[1] + wred[2] + wred[3];
            float t2 = wred[4] + wred[5] + wred[6] + wred[7];
            float m = t1 / (float)H;
            float var = fmaxf(t2 / (float)H - m * m, 0.0f);
            stats[0] = m; stats[1] = rsqrtf(var + 1e-5f);
        }
        __syncthreads();
        float m = stats[0], is = stats[1];
        float ho = (h - m) * is * rg + rb + 0.3f * hpv;
        out[(size_t)(n0 + e) * H + tid] = ho;
    }
}

extern "C" void kernel_launch(void* const* d_in, const int* in_sizes, int n_in,
                              void* d_out, int out_size, void* d_ws, size_t ws_size,
                              hipStream_t stream) {
    const float* node_emb  = (const float*)d_in[0];
    const float* h_prev    = (const float*)d_in[1];
    const float* type_emb  = (const float*)d_in[2];
    const float* W_edge    = (const float*)d_in[3];
    const float* b_edge    = (const float*)d_in[4];
    const float* ln_edge_g = (const float*)d_in[5];
    const float* ln_edge_b = (const float*)d_in[6];
    const float* W_gate    = (const float*)d_in[7];
    const float* b_gate    = (const float*)d_in[8];
    const float* ln_gate_g = (const float*)d_in[9];
    const float* ln_gate_b = (const float*)d_in[10];
    const float* W_ih      = (const float*)d_in[11];
    const float* W_hh      = (const float*)d_in[12];
    const float* b_ih      = (const float*)d_in[13];
    const float* b_hh      = (const float*)d_in[14];
    const float* ln_gru_g  = (const float*)d_in[15];
    const float* ln_gru_b  = (const float*)d_in[16];
    const int*   src       = (const int*)d_in[17];
    const int*   dst       = (const int*)d_in[18];
    const int*   et        = (const int*)d_in[19];
    float* out = (float*)d_out;

    // workspace (< 1 MiB):
    //   cntw: 50000 u32 words (u16-packed counts) = 200,000 B
    //   WTih/WThh (bf16): 2 * 196,608 * 2B        = 786,432 B
    char* ws = (char*)d_ws;
    unsigned int* cntw = (unsigned int*)ws;
    bf16* WTih = (bf16*)(ws + 200000);
    bf16* WThh = WTih + (size_t)256 * 768;

    // zero counts and the f32 agg accumulator (= d_out)
    hipMemsetAsync(cntw, 0, 200000, stream);
    hipMemsetAsync(out, 0, (size_t)N_ENTS * H * sizeof(float), stream);

    hipLaunchKernelGGL(transpose_kernel, dim3(768), dim3(256), 0, stream,
                       W_ih, W_hh, WTih, WThh);

    hipLaunchKernelGGL(edge_kernel, dim3(N_EDGES / EPB), dim3(256), 0, stream,
                       node_emb, type_emb, W_edge, b_edge, ln_edge_g, ln_edge_b,
                       src, dst, et, out, cntw);

    hipLaunchKernelGGL(node_kernel, dim3(N_ENTS / NPB), dim3(256), 0, stream,
                       node_emb, h_prev, W_gate, b_gate, ln_gate_g, ln_gate_b,
                       WTih, WThh, b_ih, b_hh, ln_gru_g, ln_gru_b,
                       cntw, out);
}